// Round 7
// baseline (559.637 us; speedup 1.0000x reference)
//
#include <hip/hip_runtime.h>
#include <hip/hip_bf16.h>

typedef short s8v __attribute__((ext_vector_type(8)));
typedef short s4v __attribute__((ext_vector_type(4)));
typedef float f4v __attribute__((ext_vector_type(4)));

#define WSTR 68    // whT [264 feat rows][68] bf16 (64 nodes + pad); 34dw rows -> 2lq bank spread
#define AP   20    // alphaS [16 (g*4+h)][16 i][20] bf16 (16 used); 10dw rows -> all-distinct banks
// bufH fragment-major: element (feat F, node n) at ((F>>5)*4 + ((F>>3)&3))*512 + n*8 + (F&7)
#define HIX(s, quad) (((s)*4 + (quad))*512)

// 4x4 grid adjacency + self loops: bit j set => j is neighbor of i
__device__ constexpr unsigned KMASK[16] = {
  0x0013u,0x0027u,0x004Eu,0x008Cu,
  0x0131u,0x0272u,0x04E4u,0x08C8u,
  0x1310u,0x2720u,0x4E40u,0x8C80u,
  0x3100u,0x7200u,0xE400u,0xC800u};

__device__ __forceinline__ short f2b(float x){            // cold paths only
  __hip_bfloat16 h = __float2bfloat16(x);
  return *reinterpret_cast<short*>(&h);
}
__device__ __forceinline__ float b2f(short s){
  __hip_bfloat16 h = *reinterpret_cast<__hip_bfloat16*>(&s);
  return __bfloat162float(h);
}
// fast RNE bf16 pair pack: low16=a, hi16=b (finite inputs)
__device__ __forceinline__ unsigned pk2(float a, float b){
  unsigned ua = __float_as_uint(a), ub = __float_as_uint(b);
  ua += 0x7fffu + ((ua >> 16) & 1u);
  ub += 0x7fffu + ((ub >> 16) & 1u);
  return __builtin_amdgcn_perm(ub, ua, 0x07060302);
}

// ======================= single prep kernel (r5/r6-validated, unchanged) =======================
__global__ __launch_bounds__(256) void prep_all(
  const float* __restrict__ W0, const float* __restrict__ as0, const float* __restrict__ ad0,
  const float* __restrict__ W1, const float* __restrict__ as1, const float* __restrict__ ad1,
  const float* __restrict__ W2, const float* __restrict__ as2, const float* __restrict__ ad2,
  const float* __restrict__ w_in,
  short* __restrict__ ws)
{
  short* WPin = ws;
  short* WP0  = ws + 2048;
  short* WP1  = ws + 2048 + 17408;
  short* WP2  = ws + 2048 + 17408 + 69632;

  const int t = threadIdx.x, l = t & 63;
  const int gid = blockIdx.x*4 + (t >> 6);

  if (gid < 288){                       // ---- main weight pack ----
    const float* W; short* WP; int u = gid, f, s, KS;
    if (u < 32)      { W = W0; WP = WP0; KS = 2; f = u >> 1; s = u & 1; }
    else if (u < 160){ u -= 32;  W = W1; WP = WP1; KS = 8; f = u >> 3; s = u & 7; }
    else             { u -= 160; W = W2; WP = WP2; KS = 8; f = u >> 3; s = u & 7; }
    const int lq = l & 15, quad = l >> 4;
    union { s8v v; short s16[8]; } o;
    #pragma unroll
    for (int j = 0; j < 8; ++j)
      o.s16[j] = f2b(W[(s*32 + quad*8 + j)*256 + f*16 + lq]);
    *(s8v*)(WP + ((f*KS + s)*64 + l)*8) = o.v;
  } else if (gid < 292){                // ---- w_in pack (A-operand layout) ----
    const int f = gid - 288;
    const int lq = l & 15, quad = l >> 4;
    union { s8v v; short s16[8]; } o;
    #pragma unroll
    for (int j = 0; j < 8; ++j){
      const int k = quad*8 + j;
      o.s16[j] = (k < 16) ? f2b(w_in[k*64 + f*16 + lq]) : (short)0;
    }
    *(s8v*)(WPin + (f*64 + l)*8) = o.v;
  } else {                              // ---- score columns, one wave per k-row ----
    int u = gid - 292;
    const float* W; const float* as; const float* ad; short* WP; int KS, k;
    if (u < 64)      { W=W0; as=as0; ad=ad0; WP=WP0; KS=2; k=u; }
    else if (u < 320){ u-=64;  W=W1; as=as1; ad=ad1; WP=WP1; KS=8; k=u; }
    else             { u-=320; W=W2; as=as2; ad=ad2; WP=WP2; KS=8; k=u; }
    float v[8];
    #pragma unroll
    for (int h = 0; h < 4; ++h){
      const float wv_ = W[k*256 + h*64 + l];
      v[h]   = wv_ * as[h*64 + l];
      v[4+h] = wv_ * ad[h*64 + l];
    }
    #pragma unroll
    for (int s = 1; s < 64; s <<= 1)
      #pragma unroll
      for (int uu = 0; uu < 8; ++uu) v[uu] += __shfl_xor(v[uu], s, 64);
    if (l < 16){
      const float r = (l < 8) ? v[l] : 0.f;
      WP[((16*KS + (k >> 5))*64 + ((k >> 3) & 3)*16 + l)*8 + (k & 7)] = f2b(r);
    }
  }
}

// ======================= main fused kernel: 4 graphs / 512 threads =======================
template<int KS, bool MEAN>
__device__ __forceinline__ void gat_layer(short* bufH, short* whT, short* alphaS,
    const short* __restrict__ WP, const float* __restrict__ bbias,
    float* gsm, const int t)
{
  const int l = t & 63, wv = t >> 6, lq = l & 15, quad = l >> 4;
  // ---- GEMM: whT[feat][node]; wave w owns f-tiles {w, w+8}; waves 4..7 add score node-tile (w-4) ----
  {
    f4v acc0[4], acc1[4], acc2;
    #pragma unroll
    for (int nt = 0; nt < 4; ++nt){
      acc0[nt] = (f4v){0.f,0.f,0.f,0.f};
      acc1[nt] = (f4v){0.f,0.f,0.f,0.f};
    }
    acc2 = (f4v){0.f,0.f,0.f,0.f};
    #pragma unroll
    for (int s = 0; s < KS; ++s){
      s8v a[4];
      #pragma unroll
      for (int nt = 0; nt < 4; ++nt)
        a[nt] = *(const s8v*)&bufH[HIX(s, quad) + (nt*16 + lq)*8];
      const s8v b0 = *(const s8v*)&WP[((wv*KS + s)*64 + l)*8];
      const s8v b1 = *(const s8v*)&WP[(((wv + 8)*KS + s)*64 + l)*8];
      #pragma unroll
      for (int nt = 0; nt < 4; ++nt){
        acc0[nt] = __builtin_amdgcn_mfma_f32_16x16x32_bf16(a[nt], b0, acc0[nt], 0,0,0);
        acc1[nt] = __builtin_amdgcn_mfma_f32_16x16x32_bf16(a[nt], b1, acc1[nt], 0,0,0);
      }
      if (wv >= 4){                                  // score tile, node-tile (wv-4)
        const s8v b2 = *(const s8v*)&WP[((16*KS + s)*64 + l)*8];
        acc2 = __builtin_amdgcn_mfma_f32_16x16x32_bf16(a[wv - 4], b2, acc2, 0,0,0);
      }
    }
    #pragma unroll
    for (int nt = 0; nt < 4; ++nt){
      uint2 p;
      p.x = pk2(acc0[nt][0], acc0[nt][1]); p.y = pk2(acc0[nt][2], acc0[nt][3]);
      *(uint2*)&whT[(wv*16 + lq)*WSTR + nt*16 + quad*4] = p;
      p.x = pk2(acc1[nt][0], acc1[nt][1]); p.y = pk2(acc1[nt][2], acc1[nt][3]);
      *(uint2*)&whT[((wv + 8)*16 + lq)*WSTR + nt*16 + quad*4] = p;
    }
    if (wv >= 4 && lq < 8){                          // score rows 256..263, cols = nodes of nt
      uint2 p;
      p.x = pk2(acc2[0], acc2[1]); p.y = pk2(acc2[2], acc2[3]);
      *(uint2*)&whT[(256 + lq)*WSTR + (wv - 4)*16 + quad*4] = p;
    }
  }
  __syncthreads();
  // ---- softmax: threads 0..255 -> (g,h,i); writes alphaS row (g*4+h, i) ----
  if (t < 256){
    const int g = t >> 6, h = (t >> 4) & 3, i = t & 15;
    const float ed = b2f(whT[(260 + h)*WSTR + g*16 + i]);
    float ev[16];
    #pragma unroll
    for (int c = 0; c < 4; ++c){
      const s4v v = *(const s4v*)&whT[(256 + h)*WSTR + g*16 + c*4];
      ev[c*4+0]=b2f(v[0]); ev[c*4+1]=b2f(v[1]); ev[c*4+2]=b2f(v[2]); ev[c*4+3]=b2f(v[3]);
    }
    const unsigned m = KMASK[i];
    float ssum = 0.f;
    #pragma unroll
    for (int j = 0; j < 16; ++j){
      float e = ed + ev[j];
      e = (e > 0.f) ? e : 0.2f*e;
      const float a = ((m >> j) & 1u) ? __expf(e) : 0.f;
      ev[j] = a; ssum += a;
    }
    const float inv = 1.f / ssum;
    unsigned* row = (unsigned*)&alphaS[((g*4 + h)*16 + i)*AP];
    #pragma unroll
    for (int c = 0; c < 8; ++c)
      row[c] = pk2(ev[2*c]*inv, ev[2*c+1]*inv);
  }
  __syncthreads();
  // ---- aggregation ----
  if constexpr (!MEAN){
    const int h = wv & 3, gp = wv >> 2;              // wave -> head, graph-pair {2gp, 2gp+1}
    union { s8v v; unsigned u[4]; } Bv[2];
    #pragma unroll
    for (int gi = 0; gi < 2; ++gi){
      const int gg = gp*2 + gi;
      const unsigned* ar = (const unsigned*)&alphaS[((gg*4 + h)*16 + lq)*AP + (quad & 1)*8];
      const bool act = ((quad >> 1) == gi);          // gg&1 == gi
      #pragma unroll
      for (int c = 0; c < 4; ++c) Bv[gi].u[c] = act ? ar[c] : 0u;
    }
    #pragma unroll
    for (int ct = 0; ct < 4; ++ct){
      const s8v a = *(const s8v*)&whT[(h*64 + ct*16 + lq)*WSTR + gp*32 + quad*8];
      const int f0 = h*64 + ct*16 + quad*4;
      const float4 bb = *(const float4*)&bbias[f0];
      const int sf = h*2 + (ct >> 1);
      const int qf = (ct & 1)*2 + (quad >> 1);
      const int jf = (quad & 1)*4;
      #pragma unroll
      for (int gi = 0; gi < 2; ++gi){
        f4v d = (f4v){0.f,0.f,0.f,0.f};
        d = __builtin_amdgcn_mfma_f32_16x16x32_bf16(a, Bv[gi].v, d, 0,0,0);
        uint2 p;
        p.x = pk2(fmaxf(d[0] + bb.x, 0.f), fmaxf(d[1] + bb.y, 0.f));
        p.y = pk2(fmaxf(d[2] + bb.z, 0.f), fmaxf(d[3] + bb.w, 0.f));
        *(uint2*)&bufH[HIX(sf, qf) + ((gp*2 + gi)*16 + lq)*8 + jf] = p;
      }
    }
  } else {
    const int g = wv >> 1, ctp = wv & 1;             // wave -> graph, ct-pair
    union { s8v v; unsigned u[4]; } Bv[4];
    #pragma unroll
    for (int h = 0; h < 4; ++h){
      const unsigned* ar = (const unsigned*)&alphaS[((g*4 + h)*16 + lq)*AP + (quad & 1)*8];
      const bool act = ((quad >> 1) == (g & 1));
      #pragma unroll
      for (int c = 0; c < 4; ++c) Bv[h].u[c] = act ? ar[c] : 0u;
    }
    #pragma unroll
    for (int cc = 0; cc < 2; ++cc){
      const int ct = ctp*2 + cc;
      f4v d = (f4v){0.f,0.f,0.f,0.f};
      #pragma unroll
      for (int h = 0; h < 4; ++h){
        const s8v a = *(const s8v*)&whT[(h*64 + ct*16 + lq)*WSTR + (g >> 1)*32 + quad*8];
        d = __builtin_amdgcn_mfma_f32_16x16x32_bf16(a, Bv[h].v, d, 0,0,0);
      }
      #pragma unroll
      for (int s = 1; s < 16; s <<= 1){
        d[0] += __shfl_xor(d[0], s, 64); d[1] += __shfl_xor(d[1], s, 64);
        d[2] += __shfl_xor(d[2], s, 64); d[3] += __shfl_xor(d[3], s, 64);
      }
      if (lq == 0){
        const int f0 = ct*16 + quad*4;
        const float4 bb = *(const float4*)&bbias[f0];
        float4 gv;
        gv.x = d[0]*(1.f/64.f) + bb.x; gv.y = d[1]*(1.f/64.f) + bb.y;
        gv.z = d[2]*(1.f/64.f) + bb.z; gv.w = d[3]*(1.f/64.f) + bb.w;
        *(float4*)&gsm[g*64 + f0] = gv;
      }
    }
  }
}

__global__ __launch_bounds__(512, 4) void gat_main(
  const float* __restrict__ x,
  const short* __restrict__ WPin, const float* __restrict__ b_in,
  const short* __restrict__ WP0,  const float* __restrict__ bb0,
  const short* __restrict__ WP1,  const float* __restrict__ bb1,
  const short* __restrict__ WP2,  const float* __restrict__ bb2,
  const float* __restrict__ w1,   const float* __restrict__ b1,
  const float* __restrict__ lng,  const float* __restrict__ lnb,
  const float* __restrict__ w2,   const float* __restrict__ b2,
  float* __restrict__ out)
{
  // Single carve: bufH 16384 + whT 17952 + alphaS 5120 = 39,456 shorts = 78,912 B -> 2 blocks/CU.
  __shared__ __align__(16) short smem[16384 + 264*WSTR + 16*16*AP];
  short* bufH   = smem;                        // fragment-major [8 s][4 quad][64 node][8]
  short* whT    = smem + 16384;                // [264][WSTR]
  short* alphaS = smem + 16384 + 264*WSTR;     // [16][16][AP]
  short* h0   = whT;                           // [64][40] staging alias (dead before whT written)
  float* gsm  = (float*)bufH;                  // [256] tail alias (bufH dead after last GEMM)
  float* ylds = gsm + 256;                     // [512]
  float* red  = gsm + 768;                     // [16]
  constexpr int H0S = 40;

  const int b = blockIdx.x;
  const int t = threadIdx.x;
  const int l = t & 63, wv = t >> 6, lq = l & 15, quad = l >> 4;

  // stage x: h0[node(4 graphs x16)][ch], zero-pad ch 16..31
  {
    const float2 v = *(const float2*)&x[(size_t)b*1024 + 2*t];
    const int i0 = 2*t;
    const int g = i0 >> 8, c = (i0 >> 4) & 15, n = i0 & 15;
    h0[(g*16 + n)*H0S + c]     = f2b(v.x);
    h0[(g*16 + n + 1)*H0S + c] = f2b(v.y);
    const int r = t >> 3, cc = 16 + 2*(t & 7);
    h0[r*H0S + cc] = 0; h0[r*H0S + cc + 1] = 0;
  }
  __syncthreads();

  // h1 = relu(h0 @ w_in + b_in) -> bufH fragment-major (feats 0..63, 64 nodes)
  {
    const int ft = wv >> 1, ntp = wv & 1;
    const s8v aF = *(const s8v*)&WPin[(ft*64 + l)*8];
    const int f0 = ft*16 + quad*4;
    const float4 bi = *(const float4*)&b_in[f0];
    const int sf = ft >> 1;
    const int qf = (ft & 1)*2 + (quad >> 1);
    const int jf = (quad & 1)*4;
    #pragma unroll
    for (int ni = 0; ni < 2; ++ni){
      const int nt = ntp*2 + ni;
      const s8v bv = *(const s8v*)&h0[(nt*16 + lq)*H0S + quad*8];
      f4v acc = (f4v){0.f,0.f,0.f,0.f};
      acc = __builtin_amdgcn_mfma_f32_16x16x32_bf16(aF, bv, acc, 0,0,0);
      uint2 p;
      p.x = pk2(fmaxf(acc[0]+bi.x,0.f), fmaxf(acc[1]+bi.y,0.f));
      p.y = pk2(fmaxf(acc[2]+bi.z,0.f), fmaxf(acc[3]+bi.w,0.f));
      *(uint2*)&bufH[HIX(sf, qf) + (nt*16 + lq)*8 + jf] = p;
    }
  }
  __syncthreads();

  gat_layer<2, false>(bufH, whT, alphaS, WP0, bb0, gsm, t);
  __syncthreads();
  gat_layer<8, false>(bufH, whT, alphaS, WP1, bb1, gsm, t);
  __syncthreads();
  gat_layer<8, true >(bufH, whT, alphaS, WP2, bb2, gsm, t);
  __syncthreads();

  // ---- MLP tail (fp32, 4 graphs): y = g@w1+b1, LN, relu, @w2+b2 ----
  const int gy = t >> 7, oy = t & 127;
  float yv = b1[oy];
  #pragma unroll 8
  for (int k = 0; k < 64; ++k) yv += gsm[gy*64 + k] * w1[k*128 + oy];
  float s1 = yv, s2 = yv*yv;
  #pragma unroll
  for (int s = 1; s < 64; s <<= 1){ s1 += __shfl_xor(s1, s, 64); s2 += __shfl_xor(s2, s, 64); }
  if ((t & 63) == 0){ red[(t>>6)*2] = s1; red[(t>>6)*2 + 1] = s2; }
  __syncthreads();
  {
    const float S1 = red[4*gy] + red[4*gy+2], S2 = red[4*gy+1] + red[4*gy+3];
    const float mu  = S1 * (1.f/128.f);
    const float var = S2 * (1.f/128.f) - mu*mu;
    const float yn  = (yv - mu) * rsqrtf(var + 1e-5f) * lng[oy] + lnb[oy];
    ylds[gy*128 + oy] = fmaxf(yn, 0.f);
  }
  __syncthreads();
  {
    const int oo = t & 255, g2 = (t >> 8)*2;
    float a0 = b2[oo], a1 = b2[oo];
    #pragma unroll 4
    for (int k = 0; k < 128; ++k){
      const float wv2 = w2[k*256 + oo];
      a0 += ylds[g2*128 + k]*wv2; a1 += ylds[(g2+1)*128 + k]*wv2;
    }
    out[((size_t)b*4 + g2)*256 + oo]     = a0;
    out[((size_t)b*4 + g2 + 1)*256 + oo] = a1;
  }
}

extern "C" void kernel_launch(void* const* d_in, const int* in_sizes, int n_in,
                              void* d_out, int out_size, void* d_ws, size_t ws_size,
                              hipStream_t stream){
  const float* x    = (const float*)d_in[0];
  const float* w_in = (const float*)d_in[1];
  const float* b_in = (const float*)d_in[2];
  const float* W0   = (const float*)d_in[3];
  const float* as0  = (const float*)d_in[4];
  const float* ad0  = (const float*)d_in[5];
  const float* bb0  = (const float*)d_in[6];
  const float* W1   = (const float*)d_in[7];
  const float* as1  = (const float*)d_in[8];
  const float* ad1  = (const float*)d_in[9];
  const float* bb1  = (const float*)d_in[10];
  const float* W2   = (const float*)d_in[11];
  const float* as2  = (const float*)d_in[12];
  const float* ad2  = (const float*)d_in[13];
  const float* bb2  = (const float*)d_in[14];
  const float* w1   = (const float*)d_in[15];
  const float* b1   = (const float*)d_in[16];
  const float* lng  = (const float*)d_in[17];
  const float* lnb  = (const float*)d_in[18];
  const float* w2   = (const float*)d_in[19];
  const float* b2   = (const float*)d_in[20];
  const int B = in_sizes[0] / 256;

  short* ws = (short*)d_ws;
  const short* WPin = ws;
  const short* WP0  = ws + 2048;
  const short* WP1  = ws + 2048 + 17408;
  const short* WP2  = ws + 2048 + 17408 + 69632;   // ends at 158,720 shorts = 317,440 B (validated)

  prep_all<<<217, 256, 0, stream>>>(W0, as0, ad0, W1, as1, ad1, W2, as2, ad2,
                                    w_in, ws);
  gat_main<<<B/4, 512, 0, stream>>>(x, WPin, b_in, WP0, bb0, WP1, bb1, WP2, bb2,
                                    w1, b1, lng, lnb, w2, b2, (float*)d_out);
}

// Round 8
// 336.579 us; speedup vs baseline: 1.6627x; 1.6627x over previous
//
#include <hip/hip_runtime.h>
#include <hip/hip_bf16.h>

typedef short s8v __attribute__((ext_vector_type(8)));
typedef short s4v __attribute__((ext_vector_type(4)));
typedef float f4v __attribute__((ext_vector_type(4)));

#define WSTR 36    // whT [264 feats][36] bf16 rows
#define AP   20    // alphaS [8 (g*4+h)][16 i][20] bf16 (16 used)
// bufH fragment-major: element (feat F, node n) at ((F>>5)*4 + ((F>>3)&3))*256 + n*8 + (F&7)
#define HIXBASE(s, quad) (((s)*4 + (quad))*256)

// 4x4 grid adjacency + self loops: bit j set => j is neighbor of i
__device__ constexpr unsigned KMASK[16] = {
  0x0013u,0x0027u,0x004Eu,0x008Cu,
  0x0131u,0x0272u,0x04E4u,0x08C8u,
  0x1310u,0x2720u,0x4E40u,0x8C80u,
  0x3100u,0x7200u,0xE400u,0xC800u};

__device__ __forceinline__ short f2b(float x){            // cold paths only
  __hip_bfloat16 h = __float2bfloat16(x);
  return *reinterpret_cast<short*>(&h);
}
__device__ __forceinline__ float b2f(short s){
  __hip_bfloat16 h = *reinterpret_cast<__hip_bfloat16*>(&s);
  return __bfloat162float(h);
}
// fast RNE bf16 pair pack: low16=a, hi16=b (finite inputs)
__device__ __forceinline__ unsigned pk2(float a, float b){
  unsigned ua = __float_as_uint(a), ub = __float_as_uint(b);
  ua += 0x7fffu + ((ua >> 16) & 1u);
  ub += 0x7fffu + ((ub >> 16) & 1u);
  return __builtin_amdgcn_perm(ub, ua, 0x07060302);
}

// ======================= single prep kernel (r5/r6-validated, unchanged) =======================
__global__ __launch_bounds__(256) void prep_all(
  const float* __restrict__ W0, const float* __restrict__ as0, const float* __restrict__ ad0,
  const float* __restrict__ W1, const float* __restrict__ as1, const float* __restrict__ ad1,
  const float* __restrict__ W2, const float* __restrict__ as2, const float* __restrict__ ad2,
  const float* __restrict__ w_in,
  short* __restrict__ ws)
{
  short* WPin = ws;
  short* WP0  = ws + 2048;
  short* WP1  = ws + 2048 + 17408;
  short* WP2  = ws + 2048 + 17408 + 69632;

  const int t = threadIdx.x, l = t & 63;
  const int gid = blockIdx.x*4 + (t >> 6);

  if (gid < 288){                       // ---- main weight pack ----
    const float* W; short* WP; int u = gid, f, s, KS;
    if (u < 32)      { W = W0; WP = WP0; KS = 2; f = u >> 1; s = u & 1; }
    else if (u < 160){ u -= 32;  W = W1; WP = WP1; KS = 8; f = u >> 3; s = u & 7; }
    else             { u -= 160; W = W2; WP = WP2; KS = 8; f = u >> 3; s = u & 7; }
    const int lq = l & 15, quad = l >> 4;
    union { s8v v; short s16[8]; } o;
    #pragma unroll
    for (int j = 0; j < 8; ++j)
      o.s16[j] = f2b(W[(s*32 + quad*8 + j)*256 + f*16 + lq]);
    *(s8v*)(WP + ((f*KS + s)*64 + l)*8) = o.v;
  } else if (gid < 292){                // ---- w_in pack (A-operand layout) ----
    const int f = gid - 288;
    const int lq = l & 15, quad = l >> 4;
    union { s8v v; short s16[8]; } o;
    #pragma unroll
    for (int j = 0; j < 8; ++j){
      const int k = quad*8 + j;
      o.s16[j] = (k < 16) ? f2b(w_in[k*64 + f*16 + lq]) : (short)0;
    }
    *(s8v*)(WPin + (f*64 + l)*8) = o.v;
  } else {                              // ---- score columns, one wave per k-row ----
    int u = gid - 292;
    const float* W; const float* as; const float* ad; short* WP; int KS, k;
    if (u < 64)      { W=W0; as=as0; ad=ad0; WP=WP0; KS=2; k=u; }
    else if (u < 320){ u-=64;  W=W1; as=as1; ad=ad1; WP=WP1; KS=8; k=u; }
    else             { u-=320; W=W2; as=as2; ad=ad2; WP=WP2; KS=8; k=u; }
    float v[8];
    #pragma unroll
    for (int h = 0; h < 4; ++h){
      const float wv_ = W[k*256 + h*64 + l];
      v[h]   = wv_ * as[h*64 + l];
      v[4+h] = wv_ * ad[h*64 + l];
    }
    #pragma unroll
    for (int s = 1; s < 64; s <<= 1)
      #pragma unroll
      for (int uu = 0; uu < 8; ++uu) v[uu] += __shfl_xor(v[uu], s, 64);
    if (l < 16){
      const float r = (l < 8) ? v[l] : 0.f;
      WP[((16*KS + (k >> 5))*64 + ((k >> 3) & 3)*16 + l)*8 + (k & 7)] = f2b(r);
    }
  }
}

// ======================= main fused kernel (r6 structure, tail removed) =======================
template<int KS, bool MEAN>
__device__ __forceinline__ void gat_layer(short* bufH, short* whT, short* alphaS,
    const short* __restrict__ WP, const float* __restrict__ bbias,
    float* __restrict__ out, const int b, const int t)
{
  const int l = t & 63, wv = t >> 6, lq = l & 15, quad = l >> 4;
  // ---- GEMM: whT[feat][node] (+ score rows 256..263); wave 3 owns the score tile ----
  {
    f4v acc[5][2];
    #pragma unroll
    for (int fi = 0; fi < 5; ++fi)
      #pragma unroll
      for (int nt = 0; nt < 2; ++nt) acc[fi][nt] = (f4v){0.f,0.f,0.f,0.f};
    #pragma unroll
    for (int s = 0; s < KS; ++s){
      const s8v a0 = *(const s8v*)&bufH[HIXBASE(s, quad) + lq*8];
      const s8v a1 = *(const s8v*)&bufH[HIXBASE(s, quad) + (16 + lq)*8];
      #pragma unroll
      for (int fi = 0; fi < 5; ++fi){
        if (fi == 4 && wv != 3) break;
        const int f = (fi == 4) ? 16 : fi*4 + wv;
        const s8v bF = *(const s8v*)&WP[((f*KS + s)*64 + l)*8];
        acc[fi][0] = __builtin_amdgcn_mfma_f32_16x16x32_bf16(a0, bF, acc[fi][0], 0,0,0);
        acc[fi][1] = __builtin_amdgcn_mfma_f32_16x16x32_bf16(a1, bF, acc[fi][1], 0,0,0);
      }
    }
    #pragma unroll
    for (int fi = 0; fi < 5; ++fi){
      if (fi == 4 && (wv != 3 || lq >= 8)) break;  // score cols 8..15 structural zeros (rows 264+ OOB)
      const int f = (fi == 4) ? 16 : fi*4 + wv;
      #pragma unroll
      for (int nt = 0; nt < 2; ++nt){
        uint2 p;
        p.x = pk2(acc[fi][nt][0], acc[fi][nt][1]);
        p.y = pk2(acc[fi][nt][2], acc[fi][nt][3]);
        *(uint2*)&whT[(f*16 + lq)*WSTR + nt*16 + quad*4] = p;
      }
    }
  }
  __syncthreads();
  // ---- softmax: thread (g,h,i) -> alphaS row (g*4+h, i), 16 bf16 ----
  if (t < 128){
    const int g = t >> 6, h = (t >> 4) & 3, i = t & 15;
    const float ed = b2f(whT[(260 + h)*WSTR + g*16 + i]);
    float ev[16];
    #pragma unroll
    for (int c = 0; c < 4; ++c){
      const s4v v = *(const s4v*)&whT[(256 + h)*WSTR + g*16 + c*4];
      ev[c*4+0]=b2f(v[0]); ev[c*4+1]=b2f(v[1]); ev[c*4+2]=b2f(v[2]); ev[c*4+3]=b2f(v[3]);
    }
    const unsigned m = KMASK[i];
    float ssum = 0.f;
    #pragma unroll
    for (int j = 0; j < 16; ++j){
      float e = ed + ev[j];
      e = (e > 0.f) ? e : 0.2f*e;
      const float a = ((m >> j) & 1u) ? __expf(e) : 0.f;
      ev[j] = a; ssum += a;
    }
    const float inv = 1.f / ssum;
    unsigned* row = (unsigned*)&alphaS[((g*4 + h)*16 + i)*AP];
    #pragma unroll
    for (int c = 0; c < 8; ++c)
      row[c] = pk2(ev[2*c]*inv, ev[2*c+1]*inv);
  }
  __syncthreads();
  // ---- aggregation: B-operand built in regs (zero half selected by quad vs g) ----
  if constexpr (!MEAN){
    const int h = wv;
    union { s8v v; unsigned u[4]; } B[2];
    #pragma unroll
    for (int g = 0; g < 2; ++g){
      const unsigned* ar = (const unsigned*)&alphaS[((g*4 + h)*16 + lq)*AP + (quad & 1)*8];
      const bool act = ((quad >> 1) == g);
      #pragma unroll
      for (int c = 0; c < 4; ++c) B[g].u[c] = act ? ar[c] : 0u;
    }
    #pragma unroll
    for (int ct = 0; ct < 4; ++ct){
      const s8v a = *(const s8v*)&whT[(h*64 + ct*16 + lq)*WSTR + quad*8];
      const int sf = h*2 + (ct >> 1);
      const int qf = (ct & 1)*2 + (quad >> 1);
      const int jf = (quad & 1)*4;
      const int f0 = h*64 + ct*16 + quad*4;
      const float4 bb = *(const float4*)&bbias[f0];
      #pragma unroll
      for (int g = 0; g < 2; ++g){
        f4v d = (f4v){0.f,0.f,0.f,0.f};
        d = __builtin_amdgcn_mfma_f32_16x16x32_bf16(a, B[g].v, d, 0,0,0);
        uint2 p;
        p.x = pk2(fmaxf(d[0] + bb.x, 0.f), fmaxf(d[1] + bb.y, 0.f));
        p.y = pk2(fmaxf(d[2] + bb.z, 0.f), fmaxf(d[3] + bb.w, 0.f));
        *(uint2*)&bufH[HIXBASE(sf, qf) + (g*16 + lq)*8 + jf] = p;
      }
    }
  } else {
    // mean over heads + node-mean pool -> g vector straight to out[(2b+g)*256 + 0..63]
    const int g = wv >> 1;
    union { s8v v; unsigned u[4]; } B[4];
    #pragma unroll
    for (int h = 0; h < 4; ++h){
      const unsigned* ar = (const unsigned*)&alphaS[((g*4 + h)*16 + lq)*AP + (quad & 1)*8];
      const bool act = ((quad >> 1) == g);
      #pragma unroll
      for (int c = 0; c < 4; ++c) B[h].u[c] = act ? ar[c] : 0u;
    }
    #pragma unroll
    for (int cc = 0; cc < 2; ++cc){
      const int ct = (wv & 1)*2 + cc;
      f4v d = (f4v){0.f,0.f,0.f,0.f};
      #pragma unroll
      for (int h = 0; h < 4; ++h){
        const s8v a = *(const s8v*)&whT[(h*64 + ct*16 + lq)*WSTR + quad*8];
        d = __builtin_amdgcn_mfma_f32_16x16x32_bf16(a, B[h].v, d, 0,0,0);
      }
      #pragma unroll
      for (int s = 1; s < 16; s <<= 1){
        d[0] += __shfl_xor(d[0], s, 64); d[1] += __shfl_xor(d[1], s, 64);
        d[2] += __shfl_xor(d[2], s, 64); d[3] += __shfl_xor(d[3], s, 64);
      }
      if (lq == 0){
        const int f0 = ct*16 + quad*4;
        const float4 bb = *(const float4*)&bbias[f0];
        float4 gv;
        gv.x = d[0]*(1.f/64.f) + bb.x; gv.y = d[1]*(1.f/64.f) + bb.y;
        gv.z = d[2]*(1.f/64.f) + bb.z; gv.w = d[3]*(1.f/64.f) + bb.w;
        *(float4*)&out[((size_t)b*2 + g)*256 + f0] = gv;
      }
    }
  }
}

__global__ __launch_bounds__(256, 4) void gat_main(
  const float* __restrict__ x,
  const short* __restrict__ WPin, const float* __restrict__ b_in,
  const short* __restrict__ WP0,  const float* __restrict__ bb0,
  const short* __restrict__ WP1,  const float* __restrict__ bb1,
  const short* __restrict__ WP2,  const float* __restrict__ bb2,
  float* __restrict__ out)
{
  // Deterministic single-carve LDS: 8192 + 9504 + 2560 = 20,256 shorts = 40,512 B -> 4 blocks/CU.
  __shared__ __align__(16) short smem[8*4*32*8 + 264*WSTR + 8*16*AP];
  short* bufH   = smem;                        // fragment-major [8 s][4 quad][32 node][8]
  short* whT    = smem + 8192;                 // [264][WSTR]
  short* alphaS = smem + 8192 + 264*WSTR;      // [8][16][AP]
  short* h0     = whT;                         // [32][40] staging alias (dead before whT written)
  constexpr int H0S = 40;

  const int b = blockIdx.x;
  const int t = threadIdx.x;
  const int l = t & 63, wv = t >> 6, lq = l & 15, quad = l >> 4;

  // stage x: h0[node][ch], zero-pad ch 16..31
  {
    const float2 v = *(const float2*)&x[b*512 + 2*t];
    const int i0 = 2*t;
    const int g = i0 >> 8, c = (i0 >> 4) & 15, n = i0 & 15;
    h0[(g*16 + n)*H0S + c]     = f2b(v.x);
    h0[(g*16 + n + 1)*H0S + c] = f2b(v.y);
    const int r = t >> 3, cc = 16 + 2*(t & 7);
    h0[r*H0S + cc] = 0; h0[r*H0S + cc + 1] = 0;
  }
  __syncthreads();

  // h1 = relu(h0 @ w_in + b_in) -> bufH fragment-major, feats 0..63
  {
    const s8v aF  = *(const s8v*)&WPin[(wv*64 + l)*8];
    const s8v b0v = *(const s8v*)&h0[lq*H0S + quad*8];
    const s8v b1v = *(const s8v*)&h0[(16+lq)*H0S + quad*8];
    f4v acc0 = (f4v){0.f,0.f,0.f,0.f}, acc1 = (f4v){0.f,0.f,0.f,0.f};
    acc0 = __builtin_amdgcn_mfma_f32_16x16x32_bf16(aF, b0v, acc0, 0,0,0);
    acc1 = __builtin_amdgcn_mfma_f32_16x16x32_bf16(aF, b1v, acc1, 0,0,0);
    const int f0 = wv*16 + quad*4;
    const float4 bi = *(const float4*)&b_in[f0];
    const int sf = wv >> 1;
    const int qf = (wv & 1)*2 + (quad >> 1);
    const int jf = (quad & 1)*4;
    uint2 p0, p1;
    p0.x = pk2(fmaxf(acc0[0]+bi.x,0.f), fmaxf(acc0[1]+bi.y,0.f));
    p0.y = pk2(fmaxf(acc0[2]+bi.z,0.f), fmaxf(acc0[3]+bi.w,0.f));
    p1.x = pk2(fmaxf(acc1[0]+bi.x,0.f), fmaxf(acc1[1]+bi.y,0.f));
    p1.y = pk2(fmaxf(acc1[2]+bi.z,0.f), fmaxf(acc1[3]+bi.w,0.f));
    *(uint2*)&bufH[HIXBASE(sf, qf) + lq*8 + jf]        = p0;
    *(uint2*)&bufH[HIXBASE(sf, qf) + (16 + lq)*8 + jf] = p1;
  }
  __syncthreads();

  gat_layer<2, false>(bufH, whT, alphaS, WP0, bb0, out, b, t);
  __syncthreads();
  gat_layer<8, false>(bufH, whT, alphaS, WP1, bb1, out, b, t);
  __syncthreads();
  gat_layer<8, true >(bufH, whT, alphaS, WP2, bb2, out, b, t);
}

// ======================= standalone MLP tail (r6-proven arithmetic) =======================
// Reads g from out[(2b+gg)*256 + 0..63] (written by gat_main), overwrites full out rows.
// All g reads complete before the first barrier; out writes happen after the second.
__global__ __launch_bounds__(256, 8) void mlp_tail(
  const float* __restrict__ w1,  const float* __restrict__ b1,
  const float* __restrict__ lng, const float* __restrict__ lnb,
  const float* __restrict__ w2,  const float* __restrict__ b2,
  float* __restrict__ out)
{
  __shared__ float ylds[256];
  __shared__ float red[8];
  const int b = blockIdx.x;
  const int t = threadIdx.x;
  const int gg = t >> 7, o = t & 127;
  const float* gptr = out + ((size_t)b*2 + gg)*256;

  float yv = b1[o];
  #pragma unroll 8
  for (int k = 0; k < 64; ++k) yv += gptr[k] * w1[k*128 + o];
  float s1 = yv, s2 = yv*yv;
  #pragma unroll
  for (int s = 1; s < 64; s <<= 1){ s1 += __shfl_xor(s1, s, 64); s2 += __shfl_xor(s2, s, 64); }
  if ((t & 63) == 0){ red[(t>>6)*2] = s1; red[(t>>6)*2 + 1] = s2; }
  __syncthreads();
  {
    const float S1 = red[4*gg] + red[4*gg+2], S2 = red[4*gg+1] + red[4*gg+3];
    const float mu  = S1 * (1.f/128.f);
    const float var = S2 * (1.f/128.f) - mu*mu;
    const float yn  = (yv - mu) * rsqrtf(var + 1e-5f) * lng[o] + lnb[o];
    ylds[gg*128 + o] = fmaxf(yn, 0.f);
  }
  __syncthreads();
  float a0 = b2[t], a1 = b2[t];
  #pragma unroll 4
  for (int k = 0; k < 128; ++k){
    const float wv2 = w2[k*256 + t];
    a0 += ylds[k]*wv2; a1 += ylds[128 + k]*wv2;
  }
  out[((size_t)b*2 + 0)*256 + t] = a0;
  out[((size_t)b*2 + 1)*256 + t] = a1;
}

extern "C" void kernel_launch(void* const* d_in, const int* in_sizes, int n_in,
                              void* d_out, int out_size, void* d_ws, size_t ws_size,
                              hipStream_t stream){
  const float* x    = (const float*)d_in[0];
  const float* w_in = (const float*)d_in[1];
  const float* b_in = (const float*)d_in[2];
  const float* W0   = (const float*)d_in[3];
  const float* as0  = (const float*)d_in[4];
  const float* ad0  = (const float*)d_in[5];
  const float* bb0  = (const float*)d_in[6];
  const float* W1   = (const float*)d_in[7];
  const float* as1  = (const float*)d_in[8];
  const float* ad1  = (const float*)d_in[9];
  const float* bb1  = (const float*)d_in[10];
  const float* W2   = (const float*)d_in[11];
  const float* as2  = (const float*)d_in[12];
  const float* ad2  = (const float*)d_in[13];
  const float* bb2  = (const float*)d_in[14];
  const float* w1   = (const float*)d_in[15];
  const float* b1   = (const float*)d_in[16];
  const float* lng  = (const float*)d_in[17];
  const float* lnb  = (const float*)d_in[18];
  const float* w2   = (const float*)d_in[19];
  const float* b2   = (const float*)d_in[20];
  const int B = in_sizes[0] / 256;

  short* ws = (short*)d_ws;
  const short* WPin = ws;
  const short* WP0  = ws + 2048;
  const short* WP1  = ws + 2048 + 17408;
  const short* WP2  = ws + 2048 + 17408 + 69632;   // ends at 158,720 shorts = 317,440 B (validated)

  prep_all<<<217, 256, 0, stream>>>(W0, as0, ad0, W1, as1, ad1, W2, as2, ad2,
                                    w_in, ws);
  gat_main<<<B/2, 256, 0, stream>>>(x, WPin, b_in, WP0, bb0, WP1, bb1, WP2, bb2,
                                    (float*)d_out);
  mlp_tail<<<B/2, 256, 0, stream>>>(w1, b1, lng, lnb, w2, b2, (float*)d_out);
}

// Round 9
// 324.764 us; speedup vs baseline: 1.7232x; 1.0364x over previous
//
#include <hip/hip_runtime.h>
#include <hip/hip_bf16.h>

typedef short s8v __attribute__((ext_vector_type(8)));
typedef short s4v __attribute__((ext_vector_type(4)));
typedef float f4v __attribute__((ext_vector_type(4)));

#define WSTR 36    // whT [264 feats][36] bf16 rows
#define AP   20    // alphaS [8 (g*4+h)][16 i][20] bf16 (16 used)
// bufH fragment-major: element (feat F, node n) at ((F>>5)*4 + ((F>>3)&3))*256 + n*8 + (F&7)
#define HIXBASE(s, quad) (((s)*4 + (quad))*256)

// 4x4 grid adjacency + self loops: bit j set => j is neighbor of i
__device__ constexpr unsigned KMASK[16] = {
  0x0013u,0x0027u,0x004Eu,0x008Cu,
  0x0131u,0x0272u,0x04E4u,0x08C8u,
  0x1310u,0x2720u,0x4E40u,0x8C80u,
  0x3100u,0x7200u,0xE400u,0xC800u};

__device__ __forceinline__ short f2b(float x){            // cold paths only
  __hip_bfloat16 h = __float2bfloat16(x);
  return *reinterpret_cast<short*>(&h);
}
__device__ __forceinline__ float b2f(short s){
  __hip_bfloat16 h = *reinterpret_cast<__hip_bfloat16*>(&s);
  return __bfloat162float(h);
}
// fast RNE bf16 pair pack: low16=a, hi16=b (finite inputs)
__device__ __forceinline__ unsigned pk2(float a, float b){
  unsigned ua = __float_as_uint(a), ub = __float_as_uint(b);
  ua += 0x7fffu + ((ua >> 16) & 1u);
  ub += 0x7fffu + ((ub >> 16) & 1u);
  return __builtin_amdgcn_perm(ub, ua, 0x07060302);
}

// ======================= single prep kernel (r5-r8 validated, unchanged) =======================
__global__ __launch_bounds__(256) void prep_all(
  const float* __restrict__ W0, const float* __restrict__ as0, const float* __restrict__ ad0,
  const float* __restrict__ W1, const float* __restrict__ as1, const float* __restrict__ ad1,
  const float* __restrict__ W2, const float* __restrict__ as2, const float* __restrict__ ad2,
  const float* __restrict__ w_in,
  short* __restrict__ ws)
{
  short* WPin = ws;
  short* WP0  = ws + 2048;
  short* WP1  = ws + 2048 + 17408;
  short* WP2  = ws + 2048 + 17408 + 69632;

  const int t = threadIdx.x, l = t & 63;
  const int gid = blockIdx.x*4 + (t >> 6);

  if (gid < 288){                       // ---- main weight pack ----
    const float* W; short* WP; int u = gid, f, s, KS;
    if (u < 32)      { W = W0; WP = WP0; KS = 2; f = u >> 1; s = u & 1; }
    else if (u < 160){ u -= 32;  W = W1; WP = WP1; KS = 8; f = u >> 3; s = u & 7; }
    else             { u -= 160; W = W2; WP = WP2; KS = 8; f = u >> 3; s = u & 7; }
    const int lq = l & 15, quad = l >> 4;
    union { s8v v; short s16[8]; } o;
    #pragma unroll
    for (int j = 0; j < 8; ++j)
      o.s16[j] = f2b(W[(s*32 + quad*8 + j)*256 + f*16 + lq]);
    *(s8v*)(WP + ((f*KS + s)*64 + l)*8) = o.v;
  } else if (gid < 292){                // ---- w_in pack (A-operand layout) ----
    const int f = gid - 288;
    const int lq = l & 15, quad = l >> 4;
    union { s8v v; short s16[8]; } o;
    #pragma unroll
    for (int j = 0; j < 8; ++j){
      const int k = quad*8 + j;
      o.s16[j] = (k < 16) ? f2b(w_in[k*64 + f*16 + lq]) : (short)0;
    }
    *(s8v*)(WPin + (f*64 + l)*8) = o.v;
  } else {                              // ---- score columns, one wave per k-row ----
    int u = gid - 292;
    const float* W; const float* as; const float* ad; short* WP; int KS, k;
    if (u < 64)      { W=W0; as=as0; ad=ad0; WP=WP0; KS=2; k=u; }
    else if (u < 320){ u-=64;  W=W1; as=as1; ad=ad1; WP=WP1; KS=8; k=u; }
    else             { u-=320; W=W2; as=as2; ad=ad2; WP=WP2; KS=8; k=u; }
    float v[8];
    #pragma unroll
    for (int h = 0; h < 4; ++h){
      const float wv_ = W[k*256 + h*64 + l];
      v[h]   = wv_ * as[h*64 + l];
      v[4+h] = wv_ * ad[h*64 + l];
    }
    #pragma unroll
    for (int s = 1; s < 64; s <<= 1)
      #pragma unroll
      for (int uu = 0; uu < 8; ++uu) v[uu] += __shfl_xor(v[uu], s, 64);
    if (l < 16){
      const float r = (l < 8) ? v[l] : 0.f;
      WP[((16*KS + (k >> 5))*64 + ((k >> 3) & 3)*16 + l)*8 + (k & 7)] = f2b(r);
    }
  }
}

// ======================= main fused kernel (r8-validated, unchanged) =======================
template<int KS, bool MEAN>
__device__ __forceinline__ void gat_layer(short* bufH, short* whT, short* alphaS,
    const short* __restrict__ WP, const float* __restrict__ bbias,
    float* __restrict__ out, const int b, const int t)
{
  const int l = t & 63, wv = t >> 6, lq = l & 15, quad = l >> 4;
  // ---- GEMM: whT[feat][node] (+ score rows 256..263); wave 3 owns the score tile ----
  {
    f4v acc[5][2];
    #pragma unroll
    for (int fi = 0; fi < 5; ++fi)
      #pragma unroll
      for (int nt = 0; nt < 2; ++nt) acc[fi][nt] = (f4v){0.f,0.f,0.f,0.f};
    #pragma unroll
    for (int s = 0; s < KS; ++s){
      const s8v a0 = *(const s8v*)&bufH[HIXBASE(s, quad) + lq*8];
      const s8v a1 = *(const s8v*)&bufH[HIXBASE(s, quad) + (16 + lq)*8];
      #pragma unroll
      for (int fi = 0; fi < 5; ++fi){
        if (fi == 4 && wv != 3) break;
        const int f = (fi == 4) ? 16 : fi*4 + wv;
        const s8v bF = *(const s8v*)&WP[((f*KS + s)*64 + l)*8];
        acc[fi][0] = __builtin_amdgcn_mfma_f32_16x16x32_bf16(a0, bF, acc[fi][0], 0,0,0);
        acc[fi][1] = __builtin_amdgcn_mfma_f32_16x16x32_bf16(a1, bF, acc[fi][1], 0,0,0);
      }
    }
    #pragma unroll
    for (int fi = 0; fi < 5; ++fi){
      if (fi == 4 && (wv != 3 || lq >= 8)) break;  // score cols 8..15 structural zeros (rows 264+ OOB)
      const int f = (fi == 4) ? 16 : fi*4 + wv;
      #pragma unroll
      for (int nt = 0; nt < 2; ++nt){
        uint2 p;
        p.x = pk2(acc[fi][nt][0], acc[fi][nt][1]);
        p.y = pk2(acc[fi][nt][2], acc[fi][nt][3]);
        *(uint2*)&whT[(f*16 + lq)*WSTR + nt*16 + quad*4] = p;
      }
    }
  }
  __syncthreads();
  // ---- softmax: thread (g,h,i) -> alphaS row (g*4+h, i), 16 bf16 ----
  if (t < 128){
    const int g = t >> 6, h = (t >> 4) & 3, i = t & 15;
    const float ed = b2f(whT[(260 + h)*WSTR + g*16 + i]);
    float ev[16];
    #pragma unroll
    for (int c = 0; c < 4; ++c){
      const s4v v = *(const s4v*)&whT[(256 + h)*WSTR + g*16 + c*4];
      ev[c*4+0]=b2f(v[0]); ev[c*4+1]=b2f(v[1]); ev[c*4+2]=b2f(v[2]); ev[c*4+3]=b2f(v[3]);
    }
    const unsigned m = KMASK[i];
    float ssum = 0.f;
    #pragma unroll
    for (int j = 0; j < 16; ++j){
      float e = ed + ev[j];
      e = (e > 0.f) ? e : 0.2f*e;
      const float a = ((m >> j) & 1u) ? __expf(e) : 0.f;
      ev[j] = a; ssum += a;
    }
    const float inv = 1.f / ssum;
    unsigned* row = (unsigned*)&alphaS[((g*4 + h)*16 + i)*AP];
    #pragma unroll
    for (int c = 0; c < 8; ++c)
      row[c] = pk2(ev[2*c]*inv, ev[2*c+1]*inv);
  }
  __syncthreads();
  // ---- aggregation: B-operand built in regs (zero half selected by quad vs g) ----
  if constexpr (!MEAN){
    const int h = wv;
    union { s8v v; unsigned u[4]; } B[2];
    #pragma unroll
    for (int g = 0; g < 2; ++g){
      const unsigned* ar = (const unsigned*)&alphaS[((g*4 + h)*16 + lq)*AP + (quad & 1)*8];
      const bool act = ((quad >> 1) == g);
      #pragma unroll
      for (int c = 0; c < 4; ++c) B[g].u[c] = act ? ar[c] : 0u;
    }
    #pragma unroll
    for (int ct = 0; ct < 4; ++ct){
      const s8v a = *(const s8v*)&whT[(h*64 + ct*16 + lq)*WSTR + quad*8];
      const int sf = h*2 + (ct >> 1);
      const int qf = (ct & 1)*2 + (quad >> 1);
      const int jf = (quad & 1)*4;
      const int f0 = h*64 + ct*16 + quad*4;
      const float4 bb = *(const float4*)&bbias[f0];
      #pragma unroll
      for (int g = 0; g < 2; ++g){
        f4v d = (f4v){0.f,0.f,0.f,0.f};
        d = __builtin_amdgcn_mfma_f32_16x16x32_bf16(a, B[g].v, d, 0,0,0);
        uint2 p;
        p.x = pk2(fmaxf(d[0] + bb.x, 0.f), fmaxf(d[1] + bb.y, 0.f));
        p.y = pk2(fmaxf(d[2] + bb.z, 0.f), fmaxf(d[3] + bb.w, 0.f));
        *(uint2*)&bufH[HIXBASE(sf, qf) + (g*16 + lq)*8 + jf] = p;
      }
    }
  } else {
    // mean over heads + node-mean pool -> g vector straight to out[(2b+g)*256 + 0..63]
    const int g = wv >> 1;
    union { s8v v; unsigned u[4]; } B[4];
    #pragma unroll
    for (int h = 0; h < 4; ++h){
      const unsigned* ar = (const unsigned*)&alphaS[((g*4 + h)*16 + lq)*AP + (quad & 1)*8];
      const bool act = ((quad >> 1) == g);
      #pragma unroll
      for (int c = 0; c < 4; ++c) B[h].u[c] = act ? ar[c] : 0u;
    }
    #pragma unroll
    for (int cc = 0; cc < 2; ++cc){
      const int ct = (wv & 1)*2 + cc;
      f4v d = (f4v){0.f,0.f,0.f,0.f};
      #pragma unroll
      for (int h = 0; h < 4; ++h){
        const s8v a = *(const s8v*)&whT[(h*64 + ct*16 + lq)*WSTR + quad*8];
        d = __builtin_amdgcn_mfma_f32_16x16x32_bf16(a, B[h].v, d, 0,0,0);
      }
      #pragma unroll
      for (int s = 1; s < 16; s <<= 1){
        d[0] += __shfl_xor(d[0], s, 64); d[1] += __shfl_xor(d[1], s, 64);
        d[2] += __shfl_xor(d[2], s, 64); d[3] += __shfl_xor(d[3], s, 64);
      }
      if (lq == 0){
        const int f0 = ct*16 + quad*4;
        const float4 bb = *(const float4*)&bbias[f0];
        float4 gv;
        gv.x = d[0]*(1.f/64.f) + bb.x; gv.y = d[1]*(1.f/64.f) + bb.y;
        gv.z = d[2]*(1.f/64.f) + bb.z; gv.w = d[3]*(1.f/64.f) + bb.w;
        *(float4*)&out[((size_t)b*2 + g)*256 + f0] = gv;
      }
    }
  }
}

__global__ __launch_bounds__(256, 4) void gat_main(
  const float* __restrict__ x,
  const short* __restrict__ WPin, const float* __restrict__ b_in,
  const short* __restrict__ WP0,  const float* __restrict__ bb0,
  const short* __restrict__ WP1,  const float* __restrict__ bb1,
  const short* __restrict__ WP2,  const float* __restrict__ bb2,
  float* __restrict__ out)
{
  // Deterministic single-carve LDS: 8192 + 9504 + 2560 = 20,256 shorts = 40,512 B -> 4 blocks/CU.
  __shared__ __align__(16) short smem[8*4*32*8 + 264*WSTR + 8*16*AP];
  short* bufH   = smem;                        // fragment-major [8 s][4 quad][32 node][8]
  short* whT    = smem + 8192;                 // [264][WSTR]
  short* alphaS = smem + 8192 + 264*WSTR;      // [8][16][AP]
  short* h0     = whT;                         // [32][40] staging alias (dead before whT written)
  constexpr int H0S = 40;

  const int b = blockIdx.x;
  const int t = threadIdx.x;
  const int l = t & 63, wv = t >> 6, lq = l & 15, quad = l >> 4;

  // stage x: h0[node][ch], zero-pad ch 16..31
  {
    const float2 v = *(const float2*)&x[b*512 + 2*t];
    const int i0 = 2*t;
    const int g = i0 >> 8, c = (i0 >> 4) & 15, n = i0 & 15;
    h0[(g*16 + n)*H0S + c]     = f2b(v.x);
    h0[(g*16 + n + 1)*H0S + c] = f2b(v.y);
    const int r = t >> 3, cc = 16 + 2*(t & 7);
    h0[r*H0S + cc] = 0; h0[r*H0S + cc + 1] = 0;
  }
  __syncthreads();

  // h1 = relu(h0 @ w_in + b_in) -> bufH fragment-major, feats 0..63
  {
    const s8v aF  = *(const s8v*)&WPin[(wv*64 + l)*8];
    const s8v b0v = *(const s8v*)&h0[lq*H0S + quad*8];
    const s8v b1v = *(const s8v*)&h0[(16+lq)*H0S + quad*8];
    f4v acc0 = (f4v){0.f,0.f,0.f,0.f}, acc1 = (f4v){0.f,0.f,0.f,0.f};
    acc0 = __builtin_amdgcn_mfma_f32_16x16x32_bf16(aF, b0v, acc0, 0,0,0);
    acc1 = __builtin_amdgcn_mfma_f32_16x16x32_bf16(aF, b1v, acc1, 0,0,0);
    const int f0 = wv*16 + quad*4;
    const float4 bi = *(const float4*)&b_in[f0];
    const int sf = wv >> 1;
    const int qf = (wv & 1)*2 + (quad >> 1);
    const int jf = (quad & 1)*4;
    uint2 p0, p1;
    p0.x = pk2(fmaxf(acc0[0]+bi.x,0.f), fmaxf(acc0[1]+bi.y,0.f));
    p0.y = pk2(fmaxf(acc0[2]+bi.z,0.f), fmaxf(acc0[3]+bi.w,0.f));
    p1.x = pk2(fmaxf(acc1[0]+bi.x,0.f), fmaxf(acc1[1]+bi.y,0.f));
    p1.y = pk2(fmaxf(acc1[2]+bi.z,0.f), fmaxf(acc1[3]+bi.w,0.f));
    *(uint2*)&bufH[HIXBASE(sf, qf) + lq*8 + jf]        = p0;
    *(uint2*)&bufH[HIXBASE(sf, qf) + (16 + lq)*8 + jf] = p1;
  }
  __syncthreads();

  gat_layer<2, false>(bufH, whT, alphaS, WP0, bb0, out, b, t);
  __syncthreads();
  gat_layer<8, false>(bufH, whT, alphaS, WP1, bb1, out, b, t);
  __syncthreads();
  gat_layer<8, true >(bufH, whT, alphaS, WP2, bb2, out, b, t);
}

// ======================= batched MLP tail: 32 graphs / block, fp32 =======================
// Reads g (cols 0..63 of each graph's out row, written by gat_main); overwrites full rows.
// All g reads complete before the first barrier; out writes happen last. Graph sets are
// block-disjoint -> no cross-block hazards.
__global__ __launch_bounds__(256) void mlp_tail(
  const float* __restrict__ w1,  const float* __restrict__ b1,
  const float* __restrict__ lng, const float* __restrict__ lnb,
  const float* __restrict__ w2,  const float* __restrict__ b2,
  float* __restrict__ out)
{
  __shared__ __align__(16) float gbuf[32*64];   //  8 KB [gr][c]
  __shared__ __align__(16) float yb[32*128];    // 16 KB [gr][o]
  __shared__ float red[64];                     // [gr]{mu, rsig}
  const int t = threadIdx.x;
  const size_t gbase = (size_t)blockIdx.x * 32;

  // phase 0: load the 32 g vectors (coalesced float4)
  #pragma unroll
  for (int u = 0; u < 2; ++u){
    const int id = u*256 + t;                   // 0..511 -> (gr, c4)
    const int gr = id >> 4, c4 = id & 15;
    const float4 v = *(const float4*)&out[(gbase + gr)*256 + c4*4];
    *(float4*)&gbuf[gr*64 + c4*4] = v;
  }
  __syncthreads();

  // phase 1: y = g @ w1 + b1. Thread: col o = t&127, half gs = t>>7 -> graphs gs*16+i.
  const int o = t & 127, gs = t >> 7;
  float w1c[64];
  #pragma unroll
  for (int k = 0; k < 64; ++k) w1c[k] = w1[k*128 + o];   // coalesced, L1/L2-hit
  const float b1v = b1[o];
  float y[16];
  #pragma unroll
  for (int i = 0; i < 16; ++i){
    const int gr = gs*16 + i;
    float acc = b1v;
    #pragma unroll
    for (int k4 = 0; k4 < 16; ++k4){                     // wave-uniform broadcast b128
      const float4 gv = *(const float4*)&gbuf[gr*64 + k4*4];
      acc += gv.x*w1c[k4*4] + gv.y*w1c[k4*4+1] + gv.z*w1c[k4*4+2] + gv.w*w1c[k4*4+3];
    }
    y[i] = acc;
    yb[gr*128 + o] = acc;
  }
  __syncthreads();

  // LN stats: thread (gr = t>>3, s = t&7), 8-lane shuffle reduce
  {
    const int gr = t >> 3, s = t & 7;
    float s1 = 0.f, s2 = 0.f;
    #pragma unroll
    for (int c4 = 0; c4 < 4; ++c4){
      const float4 v = *(const float4*)&yb[gr*128 + s*16 + c4*4];
      s1 += v.x + v.y + v.z + v.w;
      s2 += v.x*v.x + v.y*v.y + v.z*v.z + v.w*v.w;
    }
    #pragma unroll
    for (int d = 1; d < 8; d <<= 1){
      s1 += __shfl_xor(s1, d, 64);
      s2 += __shfl_xor(s2, d, 64);
    }
    if (s == 0){
      const float mu  = s1 * (1.f/128.f);
      const float var = s2 * (1.f/128.f) - mu*mu;
      red[gr*2]     = mu;
      red[gr*2 + 1] = rsqrtf(var + 1e-5f);
    }
  }
  __syncthreads();

  // LN apply + relu back into yb (same thread mapping as phase 1)
  {
    const float lg = lng[o], lb = lnb[o];
    #pragma unroll
    for (int i = 0; i < 16; ++i){
      const int gr = gs*16 + i;
      const float yn = (y[i] - red[gr*2]) * red[gr*2 + 1] * lg + lb;
      yb[gr*128 + o] = fmaxf(yn, 0.f);
    }
  }
  __syncthreads();

  // phase 2: out = relu(LN(y)) @ w2 + b2. Thread owns output col t; 16-graph register blocks.
  {
    const float b2v = b2[t];
    #pragma unroll
    for (int gh = 0; gh < 2; ++gh){
      float acc[16];
      #pragma unroll
      for (int g = 0; g < 16; ++g) acc[g] = b2v;
      #pragma unroll
      for (int kh = 0; kh < 2; ++kh){
        float w2c[64];
        #pragma unroll
        for (int k = 0; k < 64; ++k) w2c[k] = w2[(kh*64 + k)*256 + t];   // coalesced, L1-hit
        #pragma unroll
        for (int k4 = 0; k4 < 16; ++k4){
          #pragma unroll
          for (int g = 0; g < 16; ++g){                   // wave-uniform broadcast b128
            const float4 yv = *(const float4*)&yb[(gh*16 + g)*128 + kh*64 + k4*4];
            acc[g] += yv.x*w2c[k4*4] + yv.y*w2c[k4*4+1] + yv.z*w2c[k4*4+2] + yv.w*w2c[k4*4+3];
          }
        }
      }
      #pragma unroll
      for (int g = 0; g < 16; ++g)
        out[(gbase + gh*16 + g)*256 + t] = acc[g];
    }
  }
}

extern "C" void kernel_launch(void* const* d_in, const int* in_sizes, int n_in,
                              void* d_out, int out_size, void* d_ws, size_t ws_size,
                              hipStream_t stream){
  const float* x    = (const float*)d_in[0];
  const float* w_in = (const float*)d_in[1];
  const float* b_in = (const float*)d_in[2];
  const float* W0   = (const float*)d_in[3];
  const float* as0  = (const float*)d_in[4];
  const float* ad0  = (const float*)d_in[5];
  const float* bb0  = (const float*)d_in[6];
  const float* W1   = (const float*)d_in[7];
  const float* as1  = (const float*)d_in[8];
  const float* ad1  = (const float*)d_in[9];
  const float* bb1  = (const float*)d_in[10];
  const float* W2   = (const float*)d_in[11];
  const float* as2  = (const float*)d_in[12];
  const float* ad2  = (const float*)d_in[13];
  const float* bb2  = (const float*)d_in[14];
  const float* w1   = (const float*)d_in[15];
  const float* b1   = (const float*)d_in[16];
  const float* lng  = (const float*)d_in[17];
  const float* lnb  = (const float*)d_in[18];
  const float* w2   = (const float*)d_in[19];
  const float* b2   = (const float*)d_in[20];
  const int B = in_sizes[0] / 256;

  short* ws = (short*)d_ws;
  const short* WPin = ws;
  const short* WP0  = ws + 2048;
  const short* WP1  = ws + 2048 + 17408;
  const short* WP2  = ws + 2048 + 17408 + 69632;   // ends at 158,720 shorts = 317,440 B (validated)

  prep_all<<<217, 256, 0, stream>>>(W0, as0, ad0, W1, as1, ad1, W2, as2, ad2,
                                    w_in, ws);
  gat_main<<<B/2, 256, 0, stream>>>(x, WPin, b_in, WP0, bb0, WP1, bb1, WP2, bb2,
                                    (float*)d_out);
  mlp_tail<<<B/32, 256, 0, stream>>>(w1, b1, lng, lnb, w2, b2, (float*)d_out);
}

// Round 10
// 287.412 us; speedup vs baseline: 1.9472x; 1.1300x over previous
//
#include <hip/hip_runtime.h>
#include <hip/hip_bf16.h>

typedef short s8v __attribute__((ext_vector_type(8)));
typedef short s4v __attribute__((ext_vector_type(4)));
typedef float f4v __attribute__((ext_vector_type(4)));

#define WSTR 36    // whT [264 feats][36] bf16 rows
#define AP   20    // alphaS [8 (g*4+h)][16 i][20] bf16 (16 used)
// bufH fragment-major: element (feat F, node n) at ((F>>5)*4 + ((F>>3)&3))*256 + n*8 + (F&7)
#define HIXBASE(s, quad) (((s)*4 + (quad))*256)

// 4x4 grid adjacency + self loops: bit j set => j is neighbor of i
__device__ constexpr unsigned KMASK[16] = {
  0x0013u,0x0027u,0x004Eu,0x008Cu,
  0x0131u,0x0272u,0x04E4u,0x08C8u,
  0x1310u,0x2720u,0x4E40u,0x8C80u,
  0x3100u,0x7200u,0xE400u,0xC800u};

__device__ __forceinline__ short f2b(float x){            // cold paths only
  __hip_bfloat16 h = __float2bfloat16(x);
  return *reinterpret_cast<short*>(&h);
}
__device__ __forceinline__ float b2f(short s){
  __hip_bfloat16 h = *reinterpret_cast<__hip_bfloat16*>(&s);
  return __bfloat162float(h);
}
// fast RNE bf16 pair pack: low16=a, hi16=b (finite inputs)
__device__ __forceinline__ unsigned pk2(float a, float b){
  unsigned ua = __float_as_uint(a), ub = __float_as_uint(b);
  ua += 0x7fffu + ((ua >> 16) & 1u);
  ub += 0x7fffu + ((ub >> 16) & 1u);
  return __builtin_amdgcn_perm(ub, ua, 0x07060302);
}

// ======================= single prep kernel (r5-r9 validated, unchanged) =======================
__global__ __launch_bounds__(256) void prep_all(
  const float* __restrict__ W0, const float* __restrict__ as0, const float* __restrict__ ad0,
  const float* __restrict__ W1, const float* __restrict__ as1, const float* __restrict__ ad1,
  const float* __restrict__ W2, const float* __restrict__ as2, const float* __restrict__ ad2,
  const float* __restrict__ w_in,
  short* __restrict__ ws)
{
  short* WPin = ws;
  short* WP0  = ws + 2048;
  short* WP1  = ws + 2048 + 17408;
  short* WP2  = ws + 2048 + 17408 + 69632;

  const int t = threadIdx.x, l = t & 63;
  const int gid = blockIdx.x*4 + (t >> 6);

  if (gid < 288){                       // ---- main weight pack ----
    const float* W; short* WP; int u = gid, f, s, KS;
    if (u < 32)      { W = W0; WP = WP0; KS = 2; f = u >> 1; s = u & 1; }
    else if (u < 160){ u -= 32;  W = W1; WP = WP1; KS = 8; f = u >> 3; s = u & 7; }
    else             { u -= 160; W = W2; WP = WP2; KS = 8; f = u >> 3; s = u & 7; }
    const int lq = l & 15, quad = l >> 4;
    union { s8v v; short s16[8]; } o;
    #pragma unroll
    for (int j = 0; j < 8; ++j)
      o.s16[j] = f2b(W[(s*32 + quad*8 + j)*256 + f*16 + lq]);
    *(s8v*)(WP + ((f*KS + s)*64 + l)*8) = o.v;
  } else if (gid < 292){                // ---- w_in pack (A-operand layout) ----
    const int f = gid - 288;
    const int lq = l & 15, quad = l >> 4;
    union { s8v v; short s16[8]; } o;
    #pragma unroll
    for (int j = 0; j < 8; ++j){
      const int k = quad*8 + j;
      o.s16[j] = (k < 16) ? f2b(w_in[k*64 + f*16 + lq]) : (short)0;
    }
    *(s8v*)(WPin + (f*64 + l)*8) = o.v;
  } else {                              // ---- score columns, one wave per k-row ----
    int u = gid - 292;
    const float* W; const float* as; const float* ad; short* WP; int KS, k;
    if (u < 64)      { W=W0; as=as0; ad=ad0; WP=WP0; KS=2; k=u; }
    else if (u < 320){ u-=64;  W=W1; as=as1; ad=ad1; WP=WP1; KS=8; k=u; }
    else             { u-=320; W=W2; as=as2; ad=ad2; WP=WP2; KS=8; k=u; }
    float v[8];
    #pragma unroll
    for (int h = 0; h < 4; ++h){
      const float wv_ = W[k*256 + h*64 + l];
      v[h]   = wv_ * as[h*64 + l];
      v[4+h] = wv_ * ad[h*64 + l];
    }
    #pragma unroll
    for (int s = 1; s < 64; s <<= 1)
      #pragma unroll
      for (int uu = 0; uu < 8; ++uu) v[uu] += __shfl_xor(v[uu], s, 64);
    if (l < 16){
      const float r = (l < 8) ? v[l] : 0.f;
      WP[((16*KS + (k >> 5))*64 + ((k >> 3) & 3)*16 + l)*8 + (k & 7)] = f2b(r);
    }
  }
}

// ======================= main fused kernel (r8/r9-validated, unchanged) =======================
template<int KS, bool MEAN>
__device__ __forceinline__ void gat_layer(short* bufH, short* whT, short* alphaS,
    const short* __restrict__ WP, const float* __restrict__ bbias,
    float* __restrict__ out, const int b, const int t)
{
  const int l = t & 63, wv = t >> 6, lq = l & 15, quad = l >> 4;
  // ---- GEMM: whT[feat][node] (+ score rows 256..263); wave 3 owns the score tile ----
  {
    f4v acc[5][2];
    #pragma unroll
    for (int fi = 0; fi < 5; ++fi)
      #pragma unroll
      for (int nt = 0; nt < 2; ++nt) acc[fi][nt] = (f4v){0.f,0.f,0.f,0.f};
    #pragma unroll
    for (int s = 0; s < KS; ++s){
      const s8v a0 = *(const s8v*)&bufH[HIXBASE(s, quad) + lq*8];
      const s8v a1 = *(const s8v*)&bufH[HIXBASE(s, quad) + (16 + lq)*8];
      #pragma unroll
      for (int fi = 0; fi < 5; ++fi){
        if (fi == 4 && wv != 3) break;
        const int f = (fi == 4) ? 16 : fi*4 + wv;
        const s8v bF = *(const s8v*)&WP[((f*KS + s)*64 + l)*8];
        acc[fi][0] = __builtin_amdgcn_mfma_f32_16x16x32_bf16(a0, bF, acc[fi][0], 0,0,0);
        acc[fi][1] = __builtin_amdgcn_mfma_f32_16x16x32_bf16(a1, bF, acc[fi][1], 0,0,0);
      }
    }
    #pragma unroll
    for (int fi = 0; fi < 5; ++fi){
      if (fi == 4 && (wv != 3 || lq >= 8)) break;  // score cols 8..15 structural zeros (rows 264+ OOB)
      const int f = (fi == 4) ? 16 : fi*4 + wv;
      #pragma unroll
      for (int nt = 0; nt < 2; ++nt){
        uint2 p;
        p.x = pk2(acc[fi][nt][0], acc[fi][nt][1]);
        p.y = pk2(acc[fi][nt][2], acc[fi][nt][3]);
        *(uint2*)&whT[(f*16 + lq)*WSTR + nt*16 + quad*4] = p;
      }
    }
  }
  __syncthreads();
  // ---- softmax: thread (g,h,i) -> alphaS row (g*4+h, i), 16 bf16 ----
  if (t < 128){
    const int g = t >> 6, h = (t >> 4) & 3, i = t & 15;
    const float ed = b2f(whT[(260 + h)*WSTR + g*16 + i]);
    float ev[16];
    #pragma unroll
    for (int c = 0; c < 4; ++c){
      const s4v v = *(const s4v*)&whT[(256 + h)*WSTR + g*16 + c*4];
      ev[c*4+0]=b2f(v[0]); ev[c*4+1]=b2f(v[1]); ev[c*4+2]=b2f(v[2]); ev[c*4+3]=b2f(v[3]);
    }
    const unsigned m = KMASK[i];
    float ssum = 0.f;
    #pragma unroll
    for (int j = 0; j < 16; ++j){
      float e = ed + ev[j];
      e = (e > 0.f) ? e : 0.2f*e;
      const float a = ((m >> j) & 1u) ? __expf(e) : 0.f;
      ev[j] = a; ssum += a;
    }
    const float inv = 1.f / ssum;
    unsigned* row = (unsigned*)&alphaS[((g*4 + h)*16 + i)*AP];
    #pragma unroll
    for (int c = 0; c < 8; ++c)
      row[c] = pk2(ev[2*c]*inv, ev[2*c+1]*inv);
  }
  __syncthreads();
  // ---- aggregation: B-operand built in regs (zero half selected by quad vs g) ----
  if constexpr (!MEAN){
    const int h = wv;
    union { s8v v; unsigned u[4]; } B[2];
    #pragma unroll
    for (int g = 0; g < 2; ++g){
      const unsigned* ar = (const unsigned*)&alphaS[((g*4 + h)*16 + lq)*AP + (quad & 1)*8];
      const bool act = ((quad >> 1) == g);
      #pragma unroll
      for (int c = 0; c < 4; ++c) B[g].u[c] = act ? ar[c] : 0u;
    }
    #pragma unroll
    for (int ct = 0; ct < 4; ++ct){
      const s8v a = *(const s8v*)&whT[(h*64 + ct*16 + lq)*WSTR + quad*8];
      const int sf = h*2 + (ct >> 1);
      const int qf = (ct & 1)*2 + (quad >> 1);
      const int jf = (quad & 1)*4;
      const int f0 = h*64 + ct*16 + quad*4;
      const float4 bb = *(const float4*)&bbias[f0];
      #pragma unroll
      for (int g = 0; g < 2; ++g){
        f4v d = (f4v){0.f,0.f,0.f,0.f};
        d = __builtin_amdgcn_mfma_f32_16x16x32_bf16(a, B[g].v, d, 0,0,0);
        uint2 p;
        p.x = pk2(fmaxf(d[0] + bb.x, 0.f), fmaxf(d[1] + bb.y, 0.f));
        p.y = pk2(fmaxf(d[2] + bb.z, 0.f), fmaxf(d[3] + bb.w, 0.f));
        *(uint2*)&bufH[HIXBASE(sf, qf) + (g*16 + lq)*8 + jf] = p;
      }
    }
  } else {
    // mean over heads + node-mean pool -> g vector straight to out[(2b+g)*256 + 0..63]
    const int g = wv >> 1;
    union { s8v v; unsigned u[4]; } B[4];
    #pragma unroll
    for (int h = 0; h < 4; ++h){
      const unsigned* ar = (const unsigned*)&alphaS[((g*4 + h)*16 + lq)*AP + (quad & 1)*8];
      const bool act = ((quad >> 1) == g);
      #pragma unroll
      for (int c = 0; c < 4; ++c) B[h].u[c] = act ? ar[c] : 0u;
    }
    #pragma unroll
    for (int cc = 0; cc < 2; ++cc){
      const int ct = (wv & 1)*2 + cc;
      f4v d = (f4v){0.f,0.f,0.f,0.f};
      #pragma unroll
      for (int h = 0; h < 4; ++h){
        const s8v a = *(const s8v*)&whT[(h*64 + ct*16 + lq)*WSTR + quad*8];
        d = __builtin_amdgcn_mfma_f32_16x16x32_bf16(a, B[h].v, d, 0,0,0);
      }
      #pragma unroll
      for (int s = 1; s < 16; s <<= 1){
        d[0] += __shfl_xor(d[0], s, 64); d[1] += __shfl_xor(d[1], s, 64);
        d[2] += __shfl_xor(d[2], s, 64); d[3] += __shfl_xor(d[3], s, 64);
      }
      if (lq == 0){
        const int f0 = ct*16 + quad*4;
        const float4 bb = *(const float4*)&bbias[f0];
        float4 gv;
        gv.x = d[0]*(1.f/64.f) + bb.x; gv.y = d[1]*(1.f/64.f) + bb.y;
        gv.z = d[2]*(1.f/64.f) + bb.z; gv.w = d[3]*(1.f/64.f) + bb.w;
        *(float4*)&out[((size_t)b*2 + g)*256 + f0] = gv;
      }
    }
  }
}

__global__ __launch_bounds__(256, 4) void gat_main(
  const float* __restrict__ x,
  const short* __restrict__ WPin, const float* __restrict__ b_in,
  const short* __restrict__ WP0,  const float* __restrict__ bb0,
  const short* __restrict__ WP1,  const float* __restrict__ bb1,
  const short* __restrict__ WP2,  const float* __restrict__ bb2,
  float* __restrict__ out)
{
  // Deterministic single-carve LDS: 8192 + 9504 + 2560 = 20,256 shorts = 40,512 B -> 4 blocks/CU.
  __shared__ __align__(16) short smem[8*4*32*8 + 264*WSTR + 8*16*AP];
  short* bufH   = smem;                        // fragment-major [8 s][4 quad][32 node][8]
  short* whT    = smem + 8192;                 // [264][WSTR]
  short* alphaS = smem + 8192 + 264*WSTR;      // [8][16][AP]
  short* h0     = whT;                         // [32][40] staging alias (dead before whT written)
  constexpr int H0S = 40;

  const int b = blockIdx.x;
  const int t = threadIdx.x;
  const int l = t & 63, wv = t >> 6, lq = l & 15, quad = l >> 4;

  // stage x: h0[node][ch], zero-pad ch 16..31
  {
    const float2 v = *(const float2*)&x[b*512 + 2*t];
    const int i0 = 2*t;
    const int g = i0 >> 8, c = (i0 >> 4) & 15, n = i0 & 15;
    h0[(g*16 + n)*H0S + c]     = f2b(v.x);
    h0[(g*16 + n + 1)*H0S + c] = f2b(v.y);
    const int r = t >> 3, cc = 16 + 2*(t & 7);
    h0[r*H0S + cc] = 0; h0[r*H0S + cc + 1] = 0;
  }
  __syncthreads();

  // h1 = relu(h0 @ w_in + b_in) -> bufH fragment-major, feats 0..63
  {
    const s8v aF  = *(const s8v*)&WPin[(wv*64 + l)*8];
    const s8v b0v = *(const s8v*)&h0[lq*H0S + quad*8];
    const s8v b1v = *(const s8v*)&h0[(16+lq)*H0S + quad*8];
    f4v acc0 = (f4v){0.f,0.f,0.f,0.f}, acc1 = (f4v){0.f,0.f,0.f,0.f};
    acc0 = __builtin_amdgcn_mfma_f32_16x16x32_bf16(aF, b0v, acc0, 0,0,0);
    acc1 = __builtin_amdgcn_mfma_f32_16x16x32_bf16(aF, b1v, acc1, 0,0,0);
    const int f0 = wv*16 + quad*4;
    const float4 bi = *(const float4*)&b_in[f0];
    const int sf = wv >> 1;
    const int qf = (wv & 1)*2 + (quad >> 1);
    const int jf = (quad & 1)*4;
    uint2 p0, p1;
    p0.x = pk2(fmaxf(acc0[0]+bi.x,0.f), fmaxf(acc0[1]+bi.y,0.f));
    p0.y = pk2(fmaxf(acc0[2]+bi.z,0.f), fmaxf(acc0[3]+bi.w,0.f));
    p1.x = pk2(fmaxf(acc1[0]+bi.x,0.f), fmaxf(acc1[1]+bi.y,0.f));
    p1.y = pk2(fmaxf(acc1[2]+bi.z,0.f), fmaxf(acc1[3]+bi.w,0.f));
    *(uint2*)&bufH[HIXBASE(sf, qf) + lq*8 + jf]        = p0;
    *(uint2*)&bufH[HIXBASE(sf, qf) + (16 + lq)*8 + jf] = p1;
  }
  __syncthreads();

  gat_layer<2, false>(bufH, whT, alphaS, WP0, bb0, out, b, t);
  __syncthreads();
  gat_layer<8, false>(bufH, whT, alphaS, WP1, bb1, out, b, t);
  __syncthreads();
  gat_layer<8, true >(bufH, whT, alphaS, WP2, bb2, out, b, t);
}

// ======================= tail weight pack (runs AFTER gat_main; reuses dead WP1 region) =======
// w1p[((nt*2+s)*64+l)*8+j] = w1[s*32+quad*8+j][nt*16+lq]   (nt 0..7,  s 0..1)
// w2p[((nt*4+s)*64+l)*8+j] = w2[s*32+quad*8+j][nt*16+lq]   (nt 0..15, s 0..3)
__global__ __launch_bounds__(256) void prep_tail(
  const float* __restrict__ w1, const float* __restrict__ w2, short* __restrict__ ws)
{
  short* w1p = ws + 19456;            // overwrites WP1 (dead after gat_main)
  short* w2p = ws + 19456 + 8192;
  const int t = threadIdx.x, l = t & 63;
  const int task = blockIdx.x*4 + (t >> 6);     // 0..79
  const int lq = l & 15, quad = l >> 4;
  union { s8v v; short s16[8]; } o;
  if (task < 16){
    const int nt = task >> 1, s = task & 1;
    #pragma unroll
    for (int j = 0; j < 8; ++j)
      o.s16[j] = f2b(w1[(s*32 + quad*8 + j)*128 + nt*16 + lq]);
    *(s8v*)(w1p + (task*64 + l)*8) = o.v;
  } else {
    const int u = task - 16;                    // u = nt*4 + s
    const int nt = u >> 2, s = u & 3;
    #pragma unroll
    for (int j = 0; j < 8; ++j)
      o.s16[j] = f2b(w2[(s*32 + quad*8 + j)*256 + nt*16 + lq]);
    *(s8v*)(w2p + (u*64 + l)*8) = o.v;
  }
}

// ======================= MFMA MLP tail: 32 graphs / block =======================
// Reads g (cols 0..63 of each graph's out row, from gat_main); overwrites full rows.
__global__ __launch_bounds__(256) void mlp_tail(
  const short* __restrict__ w1p, const float* __restrict__ b1,
  const float* __restrict__ lng, const float* __restrict__ lnb,
  const short* __restrict__ w2p, const float* __restrict__ b2,
  float* __restrict__ out)
{
  __shared__ __align__(16) short gAF[8*32*8];     // A-frags g:  [grp k>>3][m][8]  4 KB
  __shared__ __align__(16) short yAF[16*32*8];    // A-frags y:  [grp][m][8]       8 KB
  __shared__ __align__(16) float yF[32*132];      // y fp32 [m][132]              16.5 KB
  __shared__ float red[64];                       // [m]{mu, rsig}
  const int t = threadIdx.x, l = t & 63, wv = t >> 6, lq = l & 15, quad = l >> 4;
  const size_t gbase = (size_t)blockIdx.x * 32;

  // phase 0: load g vectors, build bf16 A-fragments
  {
    const int gr = t >> 3, grp = t & 7;
    const float* gp = &out[(gbase + gr)*256 + grp*8];
    const float4 v0 = *(const float4*)gp;
    const float4 v1 = *(const float4*)(gp + 4);
    uint4 p;
    p.x = pk2(v0.x, v0.y); p.y = pk2(v0.z, v0.w);
    p.z = pk2(v1.x, v1.y); p.w = pk2(v1.z, v1.w);
    *(uint4*)&gAF[(grp*32 + gr)*8] = p;
  }
  __syncthreads();

  // phase 1: y = g @ w1 + b1  (M=32 graphs, K=64, N=128). Wave w: ntiles {2w, 2w+1}.
  {
    f4v acc[2][2];
    #pragma unroll
    for (int mt = 0; mt < 2; ++mt)
      #pragma unroll
      for (int ntl = 0; ntl < 2; ++ntl) acc[mt][ntl] = (f4v){0.f,0.f,0.f,0.f};
    #pragma unroll
    for (int s = 0; s < 2; ++s){
      const s8v a0 = *(const s8v*)&gAF[((s*4 + quad)*32 + lq)*8];
      const s8v a1 = *(const s8v*)&gAF[((s*4 + quad)*32 + 16 + lq)*8];
      #pragma unroll
      for (int ntl = 0; ntl < 2; ++ntl){
        const int nt = wv*2 + ntl;
        const s8v bv = *(const s8v*)&w1p[((nt*2 + s)*64 + l)*8];
        acc[0][ntl] = __builtin_amdgcn_mfma_f32_16x16x32_bf16(a0, bv, acc[0][ntl], 0,0,0);
        acc[1][ntl] = __builtin_amdgcn_mfma_f32_16x16x32_bf16(a1, bv, acc[1][ntl], 0,0,0);
      }
    }
    #pragma unroll
    for (int ntl = 0; ntl < 2; ++ntl){
      const int n = (wv*2 + ntl)*16 + lq;
      const float bv = b1[n];
      #pragma unroll
      for (int mt = 0; mt < 2; ++mt)
        #pragma unroll
        for (int r = 0; r < 4; ++r)
          yF[(mt*16 + quad*4 + r)*132 + n] = acc[mt][ntl][r] + bv;
    }
  }
  __syncthreads();

  // LN stats: thread (m = t>>3, s = t&7), 8-lane shuffle reduce over 128 feats
  {
    const int m = t >> 3, s = t & 7;
    float s1 = 0.f, s2 = 0.f;
    #pragma unroll
    for (int c4 = 0; c4 < 4; ++c4){
      const float4 v = *(const float4*)&yF[m*132 + s*16 + c4*4];
      s1 += v.x + v.y + v.z + v.w;
      s2 += v.x*v.x + v.y*v.y + v.z*v.z + v.w*v.w;
    }
    #pragma unroll
    for (int d = 1; d < 8; d <<= 1){ s1 += __shfl_xor(s1, d, 64); s2 += __shfl_xor(s2, d, 64); }
    if (s == 0){
      const float mu  = s1 * (1.f/128.f);
      const float var = s2 * (1.f/128.f) - mu*mu;
      red[m*2]     = mu;
      red[m*2 + 1] = rsqrtf(var + 1e-5f);
    }
  }
  __syncthreads();

  // LN apply + relu -> bf16 A-fragments for phase 2
  {
    const int m = t >> 3, s = t & 7;
    const float mu = red[m*2], rs = red[m*2 + 1];
    uint4 pa, pb;
    float v[16];
    #pragma unroll
    for (int c4 = 0; c4 < 4; ++c4){
      const float4 yv = *(const float4*)&yF[m*132 + s*16 + c4*4];
      const float4 lg = *(const float4*)&lng[s*16 + c4*4];
      const float4 lb = *(const float4*)&lnb[s*16 + c4*4];
      v[c4*4+0] = fmaxf((yv.x - mu)*rs*lg.x + lb.x, 0.f);
      v[c4*4+1] = fmaxf((yv.y - mu)*rs*lg.y + lb.y, 0.f);
      v[c4*4+2] = fmaxf((yv.z - mu)*rs*lg.z + lb.z, 0.f);
      v[c4*4+3] = fmaxf((yv.w - mu)*rs*lg.w + lb.w, 0.f);
    }
    pa.x = pk2(v[0],v[1]);  pa.y = pk2(v[2],v[3]);  pa.z = pk2(v[4],v[5]);  pa.w = pk2(v[6],v[7]);
    pb.x = pk2(v[8],v[9]);  pb.y = pk2(v[10],v[11]); pb.z = pk2(v[12],v[13]); pb.w = pk2(v[14],v[15]);
    *(uint4*)&yAF[((s*2    )*32 + m)*8] = pa;
    *(uint4*)&yAF[((s*2 + 1)*32 + m)*8] = pb;
  }
  __syncthreads();

  // phase 2: out = yA @ w2 + b2  (M=32, K=128, N=256). Wave w: ntiles {4w..4w+3}.
  {
    f4v acc[2][4];
    #pragma unroll
    for (int mt = 0; mt < 2; ++mt)
      #pragma unroll
      for (int ntl = 0; ntl < 4; ++ntl) acc[mt][ntl] = (f4v){0.f,0.f,0.f,0.f};
    #pragma unroll
    for (int s = 0; s < 4; ++s){
      const s8v a0 = *(const s8v*)&yAF[((s*4 + quad)*32 + lq)*8];
      const s8v a1 = *(const s8v*)&yAF[((s*4 + quad)*32 + 16 + lq)*8];
      #pragma unroll
      for (int ntl = 0; ntl < 4; ++ntl){
        const int nt = wv*4 + ntl;
        const s8v bv = *(const s8v*)&w2p[((nt*4 + s)*64 + l)*8];
        acc[0][ntl] = __builtin_amdgcn_mfma_f32_16x16x32_bf16(a0, bv, acc[0][ntl], 0,0,0);
        acc[1][ntl] = __builtin_amdgcn_mfma_f32_16x16x32_bf16(a1, bv, acc[1][ntl], 0,0,0);
      }
    }
    #pragma unroll
    for (int ntl = 0; ntl < 4; ++ntl){
      const int n = (wv*4 + ntl)*16 + lq;
      const float bv = b2[n];
      #pragma unroll
      for (int mt = 0; mt < 2; ++mt)
        #pragma unroll
        for (int r = 0; r < 4; ++r)
          out[(gbase + mt*16 + quad*4 + r)*256 + n] = acc[mt][ntl][r] + bv;
    }
  }
}

extern "C" void kernel_launch(void* const* d_in, const int* in_sizes, int n_in,
                              void* d_out, int out_size, void* d_ws, size_t ws_size,
                              hipStream_t stream){
  const float* x    = (const float*)d_in[0];
  const float* w_in = (const float*)d_in[1];
  const float* b_in = (const float*)d_in[2];
  const float* W0   = (const float*)d_in[3];
  const float* as0  = (const float*)d_in[4];
  const float* ad0  = (const float*)d_in[5];
  const float* bb0  = (const float*)d_in[6];
  const float* W1   = (const float*)d_in[7];
  const float* as1  = (const float*)d_in[8];
  const float* ad1  = (const float*)d_in[9];
  const float* bb1  = (const float*)d_in[10];
  const float* W2   = (const float*)d_in[11];
  const float* as2  = (const float*)d_in[12];
  const float* ad2  = (const float*)d_in[13];
  const float* bb2  = (const float*)d_in[14];
  const float* w1   = (const float*)d_in[15];
  const float* b1   = (const float*)d_in[16];
  const float* lng  = (const float*)d_in[17];
  const float* lnb  = (const float*)d_in[18];
  const float* w2   = (const float*)d_in[19];
  const float* b2   = (const float*)d_in[20];
  const int B = in_sizes[0] / 256;

  short* ws = (short*)d_ws;
  const short* WPin = ws;
  const short* WP0  = ws + 2048;
  const short* WP1  = ws + 2048 + 17408;
  const short* WP2  = ws + 2048 + 17408 + 69632;   // ends at 158,720 shorts = 317,440 B (validated)
  const short* w1p  = ws + 19456;                  // tail packs alias dead WP1 (written post-gat_main)
  const short* w2p  = ws + 19456 + 8192;

  prep_all<<<217, 256, 0, stream>>>(W0, as0, ad0, W1, as1, ad1, W2, as2, ad2,
                                    w_in, ws);
  gat_main<<<B/2, 256, 0, stream>>>(x, WPin, b_in, WP0, bb0, WP1, bb1, WP2, bb2,
                                    (float*)d_out);
  prep_tail<<<20, 256, 0, stream>>>(w1, w2, ws);
  mlp_tail<<<B/32, 256, 0, stream>>>(w1p, b1, lng, lnb, w2p, b2, (float*)d_out);
}